// Round 1
// 367.788 us; speedup vs baseline: 1.0019x; 1.0019x over previous
//
#include <hip/hip_runtime.h>
#include <hip/hip_bf16.h>
#include <stdint.h>

#define IN_DIM 256
#define HID 16
#define OUTD 10
#define BKT_SHIFT 8            // 256 nodes per bucket
#define BKT_W 256
#define PART_CH 4096           // edges per partition block
#define EPT 16                 // edges per thread in part (PART_CH/256)

typedef short v8s __attribute__((ext_vector_type(8)));
typedef float v4f __attribute__((ext_vector_type(4)));

__device__ __forceinline__ float bf2f(unsigned short u) {
    return __uint_as_float(((unsigned int)u) << 16);
}
__device__ __forceinline__ unsigned short f2bf(float f) {
    unsigned int u = __float_as_uint(f);
    unsigned int lsb = (u >> 16) & 1u;
    u += 0x7fffu + lsb;  // round-to-nearest-even
    return (unsigned short)(u >> 16);
}

__device__ __forceinline__ int load_dst(const void* ei, int n_edges, int e, int is64) {
    return is64 ? (int)((const long long*)ei)[(size_t)n_edges + e]
                : ((const int*)ei)[(size_t)n_edges + e];
}
__device__ __forceinline__ int load_src(const void* ei, int n_edges, int e, int is64) {
    return is64 ? (int)((const long long*)ei)[e] : ((const int*)ei)[e];
}

// ---------------- setup: parallel dtype detect + zero bucket counters -------
__global__ void setup_kernel(const void* __restrict__ x,
                             const void* __restrict__ W1,
                             const void* __restrict__ ei,
                             int n_nodes, int* __restrict__ flags,
                             int* __restrict__ bucket_cnt, int K) {
    int t = threadIdx.x;
    for (int i = t; i < K; i += blockDim.x) bucket_cnt[i] = 0;
    if (t < 64) {
        const unsigned short* xs = (const unsigned short*)x;
        const unsigned short* ws = (const unsigned short*)W1;
        bool badx = false, badw = false;
#pragma unroll
        for (int q = 0; q < 4; ++q) {
            float vx = bf2f(xs[t + 64 * q]);
            float vw = bf2f(ws[t + 64 * q]);
            if (!(vx > -1e4f && vx < 1e4f)) badx = true;
            if (!(vw > -1e4f && vw < 1e4f)) badw = true;
        }
        const unsigned long long* e64 = (const unsigned long long*)ei;
        bool big = false;
#pragma unroll
        for (int q = 0; q < 2; ++q)
            if (e64[t + 64 * q] >= (unsigned long long)n_nodes) big = true;
        int xf32 = __any(badx) ? 1 : 0;
        int wf32 = __any(badw) ? 1 : 0;
        int is64 = __any(big) ? 0 : 1;
        if (t == 0) { flags[0] = is64; flags[1] = xf32; flags[2] = wf32; }
    }
}

// ---------------- bucket histogram ------------------------------------------
__global__ void bhist_kernel(const void* __restrict__ ei, int n_edges,
                             int* __restrict__ bucket_cnt,
                             const int* __restrict__ flags, int K) {
    extern __shared__ int lh[];
    for (int i = threadIdx.x; i < K; i += blockDim.x) lh[i] = 0;
    __syncthreads();
    int is64 = flags[0];
    int t = blockIdx.x * blockDim.x + threadIdx.x;
    int stride = gridDim.x * blockDim.x;
    for (int e = t; e < n_edges; e += stride) {
        int d = load_dst(ei, n_edges, e, is64);
        atomicAdd(&lh[d >> BKT_SHIFT], 1);
    }
    __syncthreads();
    for (int i = threadIdx.x; i < K; i += blockDim.x)
        if (lh[i]) atomicAdd(&bucket_cnt[i], lh[i]);
}

// ---------------- bucket scan (1 block) -------------------------------------
__global__ void bscan_kernel(const int* __restrict__ bucket_cnt, int K,
                             int* __restrict__ bucket_off, int* __restrict__ bcur,
                             int* __restrict__ row_off, int n_nodes, int n_edges) {
    __shared__ int ts[256];
    int t = threadIdx.x;
    const int KP = (K + 255) / 256;   // <= 8
    int base = t * KP;
    int local[8];
    int s = 0;
    for (int q = 0; q < KP; ++q) {
        int idx = base + q;
        int v = (idx < K) ? bucket_cnt[idx] : 0;
        local[q] = v; s += v;
    }
    ts[t] = s;
    __syncthreads();
    for (int off = 1; off < 256; off <<= 1) {
        int v = (t >= off) ? ts[t - off] : 0;
        __syncthreads();
        ts[t] += v;
        __syncthreads();
    }
    int ex = ts[t] - s;
    for (int q = 0; q < KP; ++q) {
        int idx = base + q;
        if (idx < K) { bucket_off[idx] = ex; bcur[idx] = ex; }
        ex += local[q];
    }
    if (t == 255) bucket_off[K] = ex;
    if (t == 0) row_off[n_nodes] = n_edges;
}

// ---------------- partition: in-LDS counting sort + coalesced flush ---------
// pair = (src << 8) | (dst & 255): 4B packed.
__global__ void part_kernel(const void* __restrict__ ei, int n_edges,
                            int* __restrict__ bcur, unsigned int* __restrict__ pairs,
                            const int* __restrict__ flags, int K) {
    __shared__ int lh[512];                  // counts, then placement cursor
    __shared__ int gdelta[512];              // gstart[b] - lstart[b]
    __shared__ int ts[256];
    __shared__ unsigned int spairs[PART_CH]; // 16 KiB
    __shared__ unsigned short sbkt[PART_CH]; // 8 KiB
    int begin = blockIdx.x * PART_CH;
    int is64 = flags[0];
    int t = threadIdx.x;
    lh[t] = 0; lh[t + 256] = 0;

    int dloc[EPT];
#pragma unroll
    for (int i = 0; i < EPT; ++i) {
        int e = begin + i * 256 + t;
        dloc[i] = (e < n_edges) ? load_dst(ei, n_edges, e, is64) : -1;
    }
    __syncthreads();
#pragma unroll
    for (int i = 0; i < EPT; ++i)
        if (dloc[i] >= 0) atomicAdd(&lh[dloc[i] >> BKT_SHIFT], 1);
    __syncthreads();

    // block scan over 512 bucket counts (thread t owns entries 2t, 2t+1)
    int c0 = lh[2 * t], c1 = lh[2 * t + 1];
    int s = c0 + c1;
    ts[t] = s;
    __syncthreads();
    for (int off = 1; off < 256; off <<= 1) {
        int v = (t >= off) ? ts[t - off] : 0;
        __syncthreads();
        ts[t] += v;
        __syncthreads();
    }
    int ex = ts[t] - s;
    // reserve global runs; cursor = local exclusive start
    if (c0 > 0) gdelta[2 * t]     = atomicAdd(&bcur[2 * t], c0) - ex;
    if (c1 > 0) gdelta[2 * t + 1] = atomicAdd(&bcur[2 * t + 1], c1) - (ex + c0);
    __syncthreads();   // everyone done reading lh counts before overwrite
    lh[2 * t] = ex; lh[2 * t + 1] = ex + c0;
    __syncthreads();

    // place into LDS, sorted by bucket
#pragma unroll
    for (int i = 0; i < EPT; ++i) {
        int e = begin + i * 256 + t;
        if (dloc[i] >= 0) {
            int srcv = load_src(ei, n_edges, e, is64);
            int b = dloc[i] >> BKT_SHIFT;
            int lpos = atomicAdd(&lh[b], 1);
            spairs[lpos] = ((unsigned)srcv << 8) | ((unsigned)dloc[i] & (BKT_W - 1));
            sbkt[lpos] = (unsigned short)b;
        }
    }
    __syncthreads();

    // coalesced flush: ascending j walks bucket runs contiguously
    int total = n_edges - begin; if (total > PART_CH) total = PART_CH;
    for (int j = t; j < total; j += 256)
        pairs[gdelta[sbkt[j]] + j] = spairs[j];
}

// ---------------- per-bucket CSR build (256-node buckets, 512 thr) ----------
__global__ void csr_kernel(const unsigned int* __restrict__ pairs,
                           const int* __restrict__ bucket_off,
                           int* __restrict__ row_off, int* __restrict__ csr_src,
                           int n_nodes) {
    __shared__ int deg[BKT_W];
    __shared__ int cur[BKT_W];
    __shared__ int ts[BKT_W];
    int blk = blockIdx.x;
    int nbase = blk << BKT_SHIFT;
    int NL = n_nodes - nbase; if (NL > BKT_W) NL = BKT_W;
    int beg = bucket_off[blk], end = bucket_off[blk + 1];
    int t = threadIdx.x;
    if (t < BKT_W) deg[t] = 0;
    __syncthreads();
    for (int k = beg + t; k < end; k += blockDim.x)
        atomicAdd(&deg[pairs[k] & (BKT_W - 1)], 1);
    __syncthreads();
    if (t < BKT_W) ts[t] = deg[t];
    __syncthreads();
    for (int off = 1; off < BKT_W; off <<= 1) {
        int v = 0;
        if (t < BKT_W && t >= off) v = ts[t - off];
        __syncthreads();
        if (t < BKT_W) ts[t] += v;
        __syncthreads();
    }
    if (t < BKT_W) {
        int ex = beg + ts[t] - deg[t];
        cur[t] = ex;
        if (t < NL) row_off[nbase + t] = ex;
    }
    __syncthreads();
    for (int k = beg + t; k < end; k += blockDim.x) {
        unsigned int p = pairs[k];
        int pos = atomicAdd(&cur[p & (BKT_W - 1)], 1);
        csr_src[pos] = (int)(p >> 8);
    }
}

// ---------------- gemm1 (MFMA, bf16 x): m1 = x @ W1 -------------------------
__global__ void gemm1_mfma_bf16x(const unsigned short* __restrict__ x,
                                 const void* __restrict__ W1p,
                                 float* __restrict__ m1, int n_nodes,
                                 const int* __restrict__ flags) {
    if (flags[1]) return;              // fp32 x handled elsewhere
    const int wf32 = flags[2];
    __shared__ unsigned short Bl[8 * 64 * 8];  // [kk][lane][j], 8 KiB
    int t = threadIdx.x;
    for (int i = t; i < 4096; i += 256) {      // i = k*16 + n
        unsigned short w = wf32 ? f2bf(((const float*)W1p)[i])
                                : ((const unsigned short*)W1p)[i];
        int k = i >> 4, n = i & 15;
        int kk = k >> 5, quad = (k >> 3) & 3, j = k & 7;
        Bl[((kk * 4 + quad) * 16 + n) * 8 + j] = w;
    }
    __syncthreads();

    int lane = t & 63;
    int wave = t >> 6;
    v8s bfrag[8];
#pragma unroll
    for (int kk = 0; kk < 8; ++kk)
        bfrag[kk] = *(const v8s*)&Bl[(kk * 64 + lane) * 8];

    int col  = lane & 15;
    int quad = lane >> 4;
    int n_tiles = (n_nodes + 15) >> 4;
    for (int tile = blockIdx.x * 4 + wave; tile < n_tiles; tile += gridDim.x * 4) {
        int row = tile * 16 + col;
        int r = row < n_nodes ? row : n_nodes - 1;
        const unsigned short* xp = x + (size_t)r * IN_DIM + quad * 8;
        // prefetch all 8 fragments (independent loads in flight)
        v8s a[8];
#pragma unroll
        for (int kk = 0; kk < 8; ++kk)
            a[kk] = *(const v8s*)(xp + kk * 32);
        v4f acc = {0.f, 0.f, 0.f, 0.f};
#pragma unroll
        for (int kk = 0; kk < 8; ++kk)
            acc = __builtin_amdgcn_mfma_f32_16x16x32_bf16(a[kk], bfrag[kk], acc, 0, 0, 0);
#pragma unroll
        for (int rg = 0; rg < 4; ++rg) {
            int node = tile * 16 + quad * 4 + rg;
            if (node < n_nodes) m1[(size_t)node * HID + col] = acc[rg];
        }
    }
}

// ---------------- gemm1 (MFMA, fp32 x): split-bf16, fp32-grade precision ----
// Latency fix vs prior version: whole per-lane row slice (16 x dwordx4)
// prefetched into regs before the convert/MFMA loop; B fragments read from
// LDS inside the loop (keeps VGPR <= 128 for 4 waves/EU); grid sized to
// tile count by host (was 512 blocks -> 17.8% occupancy, 970 GB/s).
__global__ __launch_bounds__(256, 4) void gemm1_mfma_f32x(
                                const float* __restrict__ x,
                                const void* __restrict__ W1p,
                                float* __restrict__ m1, int n_nodes,
                                const int* __restrict__ flags) {
    if (!flags[1]) return;             // bf16 x handled elsewhere
    const int wf32 = flags[2];
    __shared__ unsigned short Bhi[8 * 64 * 8];
    __shared__ unsigned short Blo[8 * 64 * 8];
    int t = threadIdx.x;
    for (int i = t; i < 4096; i += 256) {
        float w = wf32 ? ((const float*)W1p)[i]
                       : bf2f(((const unsigned short*)W1p)[i]);
        unsigned short hi = f2bf(w);
        unsigned short lo = f2bf(w - bf2f(hi));
        int k = i >> 4, n = i & 15;
        int kk = k >> 5, quad = (k >> 3) & 3, j = k & 7;
        int idx = ((kk * 4 + quad) * 16 + n) * 8 + j;
        Bhi[idx] = hi; Blo[idx] = lo;
    }
    __syncthreads();

    int lane = t & 63;
    int wave = t >> 6;
    int col  = lane & 15;
    int quad = lane >> 4;
    int n_tiles = (n_nodes + 15) >> 4;
    for (int tile = blockIdx.x * 4 + wave; tile < n_tiles; tile += gridDim.x * 4) {
        int row = tile * 16 + col;
        int r = row < n_nodes ? row : n_nodes - 1;
        const float* xp = x + (size_t)r * IN_DIM + quad * 8;
        // prefetch: 16 independent dwordx4 loads (64 floats/lane)
        float4 u[16];
#pragma unroll
        for (int kk = 0; kk < 8; ++kk) {
            u[2 * kk]     = *(const float4*)(xp + kk * 32);
            u[2 * kk + 1] = *(const float4*)(xp + kk * 32 + 4);
        }
        v4f acc = {0.f, 0.f, 0.f, 0.f};
#pragma unroll
        for (int kk = 0; kk < 8; ++kk) {
            float uv[8] = {u[2 * kk].x,     u[2 * kk].y,
                           u[2 * kk].z,     u[2 * kk].w,
                           u[2 * kk + 1].x, u[2 * kk + 1].y,
                           u[2 * kk + 1].z, u[2 * kk + 1].w};
            v8s ahi, alo;
#pragma unroll
            for (int j = 0; j < 8; ++j) {
                unsigned short hi = f2bf(uv[j]);
                unsigned short lo = f2bf(uv[j] - bf2f(hi));
                ahi[j] = (short)hi; alo[j] = (short)lo;
            }
            v8s bh = *(const v8s*)&Bhi[(kk * 64 + lane) * 8];
            v8s bl = *(const v8s*)&Blo[(kk * 64 + lane) * 8];
            acc = __builtin_amdgcn_mfma_f32_16x16x32_bf16(ahi, bh, acc, 0, 0, 0);
            acc = __builtin_amdgcn_mfma_f32_16x16x32_bf16(ahi, bl, acc, 0, 0, 0);
            acc = __builtin_amdgcn_mfma_f32_16x16x32_bf16(alo, bh, acc, 0, 0, 0);
        }
#pragma unroll
        for (int rg = 0; rg < 4; ++rg) {
            int node = tile * 16 + quad * 4 + rg;
            if (node < n_nodes) m1[(size_t)node * HID + col] = acc[rg];
        }
    }
}

// ---------------- gather-sum core: 4 lanes/node, 16-deep MLP ----------------
__device__ __forceinline__ float4 gather_sum16(const float* __restrict__ src,
                                               const int* __restrict__ csr_src,
                                               int beg, int end, int q) {
    float ax = 0.f, ay = 0.f, az = 0.f, aw = 0.f;
    int k = beg;
    for (; k + 16 <= end; k += 16) {
        float4 v[16];
#pragma unroll
        for (int u = 0; u < 16; ++u) {
            int s = csr_src[k + u];
            v[u] = *((const float4*)(src + (size_t)s * HID) + q);
        }
#pragma unroll
        for (int u = 0; u < 16; ++u) {
            ax += v[u].x; ay += v[u].y; az += v[u].z; aw += v[u].w;
        }
    }
    for (; k + 4 <= end; k += 4) {
        float4 v[4];
#pragma unroll
        for (int u = 0; u < 4; ++u) {
            int s = csr_src[k + u];
            v[u] = *((const float4*)(src + (size_t)s * HID) + q);
        }
#pragma unroll
        for (int u = 0; u < 4; ++u) {
            ax += v[u].x; ay += v[u].y; az += v[u].z; aw += v[u].w;
        }
    }
    for (; k < end; ++k) {
        int s = csr_src[k];
        float4 v = *((const float4*)(src + (size_t)s * HID) + q);
        ax += v.x; ay += v.y; az += v.z; aw += v.w;
    }
    return make_float4(ax, ay, az, aw);
}

// ---------------- agg1: h = relu(A . m1 + b1) -------------------------------
__global__ void agg1_kernel(const float* __restrict__ m1,
                            const int* __restrict__ row_off,
                            const int* __restrict__ csr_src,
                            const void* __restrict__ b1p,
                            float* __restrict__ h, int n_nodes,
                            const int* __restrict__ flags) {
    int t = blockIdx.x * blockDim.x + threadIdx.x;
    int node = t >> 2;
    if (node >= n_nodes) return;
    int q = t & 3;
    const int wf32 = flags[2];
    float4 a = gather_sum16(m1, csr_src, row_off[node], row_off[node + 1], q);
    float b0, b1v, b2v, b3;
    if (wf32) {
        const float* b = (const float*)b1p + q * 4;
        b0 = b[0]; b1v = b[1]; b2v = b[2]; b3 = b[3];
    } else {
        const unsigned short* b = (const unsigned short*)b1p + q * 4;
        b0 = bf2f(b[0]); b1v = bf2f(b[1]); b2v = bf2f(b[2]); b3 = bf2f(b[3]);
    }
    float4 r;
    r.x = fmaxf(a.x + b0, 0.f);
    r.y = fmaxf(a.y + b1v, 0.f);
    r.z = fmaxf(a.z + b2v, 0.f);
    r.w = fmaxf(a.w + b3, 0.f);
    *((float4*)(h + (size_t)node * HID) + q) = r;
}

// ---------------- agg2 + out fused: out = (A . h) @ W2 + b2 -----------------
// Each node is handled by 4 consecutive lanes (quads of the wave). Each lane
// gathers its 4 h-components, forms partial dot products against W2, then a
// 4-lane shfl_xor reduce yields the full 10-wide output in every lane.
// Saves the aggh round-trip (6.4 MB write + 6.4 MB read) and one launch.
__global__ void agg2_out_kernel(const float* __restrict__ h,
                                const int* __restrict__ row_off,
                                const int* __restrict__ csr_src,
                                const void* __restrict__ W2p,
                                const void* __restrict__ b2p,
                                void* __restrict__ out, int n_nodes,
                                const int* __restrict__ flags) {
    __shared__ float Ws[HID * OUTD];
    __shared__ float bs[OUTD];
    const int xf32 = flags[1], wf32 = flags[2];
    if (threadIdx.x < HID * OUTD)
        Ws[threadIdx.x] = wf32 ? ((const float*)W2p)[threadIdx.x]
                               : bf2f(((const unsigned short*)W2p)[threadIdx.x]);
    if (threadIdx.x < OUTD)
        bs[threadIdx.x] = wf32 ? ((const float*)b2p)[threadIdx.x]
                               : bf2f(((const unsigned short*)b2p)[threadIdx.x]);
    __syncthreads();

    int t = blockIdx.x * blockDim.x + threadIdx.x;
    int node = t >> 2;
    if (node >= n_nodes) return;
    int q = t & 3;
    float4 a = gather_sum16(h, csr_src, row_off[node], row_off[node + 1], q);

    float av[4] = {a.x, a.y, a.z, a.w};
    float o[OUTD];
#pragma unroll
    for (int od = 0; od < OUTD; ++od) {
        float s = 0.f;
#pragma unroll
        for (int j = 0; j < 4; ++j)
            s = fmaf(av[j], Ws[(q * 4 + j) * OUTD + od], s);
        o[od] = s;
    }
#pragma unroll
    for (int od = 0; od < OUTD; ++od) {
        o[od] += __shfl_xor(o[od], 1);
        o[od] += __shfl_xor(o[od], 2);
        o[od] += bs[od];
    }

    if (xf32) {
        float2* po = (float2*)((float*)out + (size_t)node * OUTD);
        if (q == 0) {
            po[0] = make_float2(o[0], o[1]);
            po[1] = make_float2(o[2], o[3]);
        } else if (q == 1) {
            po[2] = make_float2(o[4], o[5]);
            po[3] = make_float2(o[6], o[7]);
        } else if (q == 2) {
            po[4] = make_float2(o[8], o[9]);
        }
    } else {
        unsigned int* po = (unsigned int*)((unsigned short*)out + (size_t)node * OUTD);
        if (q == 0) {
            po[0] = (unsigned int)f2bf(o[0]) | ((unsigned int)f2bf(o[1]) << 16);
            po[1] = (unsigned int)f2bf(o[2]) | ((unsigned int)f2bf(o[3]) << 16);
        } else if (q == 1) {
            po[2] = (unsigned int)f2bf(o[4]) | ((unsigned int)f2bf(o[5]) << 16);
            po[3] = (unsigned int)f2bf(o[6]) | ((unsigned int)f2bf(o[7]) << 16);
        } else if (q == 2) {
            po[4] = (unsigned int)f2bf(o[8]) | ((unsigned int)f2bf(o[9]) << 16);
        }
    }
}

// ---------------- Sentinel: ws_size too small -------------------------------
__global__ void sentinel_kernel(float* __restrict__ out) {
    if (blockIdx.x == 0 && threadIdx.x < 16) out[threadIdx.x] = 123456.0f;
}

extern "C" void kernel_launch(void* const* d_in, const int* in_sizes, int n_in,
                              void* d_out, int out_size, void* d_ws, size_t ws_size,
                              hipStream_t stream) {
    const void* x  = d_in[0];
    const void* ei = d_in[1];
    const void* W1 = d_in[2];
    const void* b1 = d_in[3];
    const void* W2 = d_in[4];
    const void* b2 = d_in[5];

    const int n_nodes = in_sizes[0] / IN_DIM;        // 100000
    const int n_edges = in_sizes[1] / 2;             // 3200000
    const int K = (n_nodes + BKT_W - 1) / BKT_W;     // 391 buckets

    // Workspace layout (256B-aligned):
    // [flags | bucket_cnt | bucket_off | bcur | row_off | csr_src |
    //  pairs-region (aliases m1,h after csr build)]
    char* p = (char*)d_ws;
    auto align = [](size_t v) { return (v + 255) & ~(size_t)255; };
    size_t off = 0;
    int* flags      = (int*)(p + off); off = align(off + 256);
    int* bucket_cnt = (int*)(p + off); off = align(off + (size_t)K * 4);
    int* bucket_off = (int*)(p + off); off = align(off + ((size_t)K + 1) * 4);
    int* bcur       = (int*)(p + off); off = align(off + (size_t)K * 4);
    int* row_off    = (int*)(p + off); off = align(off + ((size_t)n_nodes + 1) * 4);
    int* csr_src    = (int*)(p + off); off = align(off + (size_t)n_edges * 4);
    size_t alias_base = off;
    unsigned int* pairs = (unsigned int*)(p + alias_base);
    float* m1    = (float*)(p + alias_base);          // aliases pairs (stream-ordered)
    float* h     = m1 + (size_t)n_nodes * HID;
    size_t alias_sz = (size_t)n_edges * 4;            // packed pairs
    size_t mhm_sz = (size_t)n_nodes * (HID * 3) * 4;  // keep prior margin
    if (mhm_sz > alias_sz) alias_sz = mhm_sz;
    off = align(alias_base + alias_sz);

    if (ws_size < off) {
        sentinel_kernel<<<1, 64, 0, stream>>>((float*)d_out);
        return;
    }

    const size_t lds_k = (size_t)K * 4;

    // --- CSR build (bucketed, LDS counting-sort, line-efficient writes) ---
    setup_kernel<<<1, 256, 0, stream>>>(x, W1, ei, n_nodes, flags, bucket_cnt, K);
    bhist_kernel<<<1024, 256, lds_k, stream>>>(ei, n_edges, bucket_cnt, flags, K);
    bscan_kernel<<<1, 256, 0, stream>>>(bucket_cnt, K, bucket_off, bcur,
                                        row_off, n_nodes, n_edges);
    part_kernel<<<(n_edges + PART_CH - 1) / PART_CH, 256, 0, stream>>>(
        ei, n_edges, bcur, pairs, flags, K);
    csr_kernel<<<K, 512, 0, stream>>>(pairs, bucket_off, row_off, csr_src, n_nodes);

    // --- layer 1 ---
    {
        int n_tiles16 = (n_nodes + 15) >> 4;          // 6250
        int g1 = (n_tiles16 + 3) / 4;                 // 1 tile per wave
        gemm1_mfma_bf16x<<<g1, 256, 0, stream>>>(
            (const unsigned short*)x, W1, m1, n_nodes, flags);
        gemm1_mfma_f32x<<<g1, 256, 0, stream>>>(
            (const float*)x, W1, m1, n_nodes, flags);
    }
    {
        long long threads = (long long)n_nodes * 4;
        agg1_kernel<<<(int)((threads + 255) / 256), 256, 0, stream>>>(
            m1, row_off, csr_src, b1, h, n_nodes, flags);
    }

    // --- layer 2 fused (assoc: out = (A.h)@W2 + b2) ---
    {
        long long threads = (long long)n_nodes * 4;
        agg2_out_kernel<<<(int)((threads + 255) / 256), 256, 0, stream>>>(
            h, row_off, csr_src, W2, b2, d_out, n_nodes, flags);
    }
}